// Round 8
// baseline (1361.459 us; speedup 1.0000x reference)
//
#include <hip/hip_runtime.h>
#include <cmath>

// CfC encoder: 3-layer liquid-NN recurrence, B=512, K=64 steps, fp32 io.
// R10: VMEM-issue-throughput attack. R4-R9 established: not latency-, TLP-,
// or batching-bound; ~327K 1KB load-instructions/step at ~16cyc/instr is the
// floor. This version gives each WAVE a 64-row x 16-col tile: the 4 weight
// fragments are loaded once per wave and reused across 4 m-subtiles
// (12 loads + 32 MFMA per chunk vs the old 4-wave block's 24 + 32).
// Chip-wide load instructions halve. Waves in a block take adjacent nt, so
// act fragments are L1-shared. Ring depth D=2, counted vmcnt, as R6.
// Roles per step s: XPREP(s+2) | XGEMM(s+1) | L0rec(s) | L1(s-1) | L2(s-2).

typedef __attribute__((ext_vector_type(8))) _Float16 half8;
typedef __attribute__((ext_vector_type(4))) float f32x4;

#define DEVINL __device__ __forceinline__

struct Params {
  const float* base;    // (512,64,256)
  const float* visual;  // (512,64,512)
  const _Float16 *w0, *w1, *w2;   // packed [g][nt][c][lane][8]
  const float *b0f1,*b0f2,*b0ta,*b0tb;
  const float *b1f1,*b1f2,*b1ta,*b1tb;
  const float *b2f1,*b2f2,*b2ta,*b2tb;
  _Float16 *xh0,*xl0,*xh1,*xl1;   // x planes packed [mt16][c(24)][lane][8]
  float *xacc0,*xacc1;            // x pre-GEMM out, double buffer (512*2048) fp32
  _Float16 *h0h0,*h0h1,*h0l0,*h0l1;   // h planes packed [mt16][c(HH/32)][lane][8]
  _Float16 *h1h0,*h1h1,*h1l0,*h1l1;
  _Float16 *h2h0,*h2h1,*h2l0,*h2l1;
  float* out;
};

// ---- asm load + counted-vmcnt wait primitives ----
DEVINL void gload(half8& d, const _Float16* a) {
  asm volatile("global_load_dwordx4 %0, %1, off" : "=v"(d) : "v"(a));
}
template <int V>
DEVINL void vmwait() {
  // gfx9 waitcnt encoding: vmcnt[3:0]|expcnt[6:4]|lgkmcnt[11:8]|vmcnt_hi[15:14]
  __builtin_amdgcn_s_waitcnt((V & 15) | (7 << 4) | (15 << 8) | ((V >> 4) << 14));
  __builtin_amdgcn_sched_barrier(0);   // rule #18: stop MFMA hoist above wait
}

// ---- depth-D ring pipelined GEMM, J=12 loads/chunk ----
// j: 0..3 weight gate frags | 4..7 act-hi frag (m-subtile s=j-4) | 8..11 act-lo.
template <int C, int NC, int D, class AF>
DEVINL void pipe_iter(half8 (&buf)[D][12], f32x4 (&acc)[4][4], const AF& addr) {
  constexpr int issued = (C + D < NC) ? (C + D) : NC;
  vmwait<12 * (issued - C - 1)>();     // oldest chunk (C) has landed
  {
    half8 (&B)[12] = buf[C % D];
    // hi pass: each acc[s][g] touched once (dependency distance 16)
#pragma unroll
    for (int s = 0; s < 4; ++s)
#pragma unroll
      for (int g = 0; g < 4; ++g)
        acc[s][g] = __builtin_amdgcn_mfma_f32_16x16x32_f16(B[4 + s], B[g], acc[s][g], 0, 0, 0);
    // lo pass
#pragma unroll
    for (int s = 0; s < 4; ++s)
#pragma unroll
      for (int g = 0; g < 4; ++g)
        acc[s][g] = __builtin_amdgcn_mfma_f32_16x16x32_f16(B[8 + s], B[g], acc[s][g], 0, 0, 0);
  }
  if constexpr (C + D < NC) {
#pragma unroll
    for (int j = 0; j < 12; ++j) gload(buf[C % D][j], addr(C + D, j));
  }
  if constexpr (C + 1 < NC) pipe_iter<C + 1, NC, D>(buf, acc, addr);
}

template <int NC, class AF>
DEVINL void gemm_pipe(f32x4 (&acc)[4][4], const AF& addr) {
  constexpr int D = (NC < 2) ? NC : 2;
  half8 buf[D][12];
#pragma unroll
  for (int c = 0; c < D; ++c)
#pragma unroll
    for (int j = 0; j < 12; ++j) gload(buf[c][j], addr(c, j));
  pipe_iter<0, NC, D>(buf, acc, addr);
}

// ---- role: split x(t) fp32 -> fp16 hi/lo packed planes (buf t&1) ----
DEVINL void run_xprep(const Params& p, int t, int b /*0..47*/) {
  _Float16* xh = (t & 1) ? p.xh1 : p.xh0;
  _Float16* xl = (t & 1) ? p.xl1 : p.xl0;
  int tid = b * 256 + threadIdx.x;            // 12288 threads
#pragma unroll
  for (int i = tid; i < 49152; i += 12288) {  // 512 rows * 96 groups of 8
    int m = i / 96;
    int k = (i - m * 96) * 8;
    const float* src = (k < 256) ? (p.base + (m * 64 + t) * 256 + k)
                                 : (p.visual + (m * 64 + t) * 512 + (k - 256));
    const f32x4* q = (const f32x4*)src;
    f32x4 v0 = q[0], v1 = q[1];
    half8 hh, ll;
#pragma unroll
    for (int j = 0; j < 4; ++j) {
      _Float16 a = (_Float16)v0[j]; hh[j] = a;     ll[j]     = (_Float16)(v0[j] - (float)a);
      _Float16 c = (_Float16)v1[j]; hh[j + 4] = c; ll[j + 4] = (_Float16)(v1[j] - (float)c);
    }
    // packed: [mt16 = m>>4][c = k>>5][lane = ((k>>3)&3)*16 + (m&15)][8]
    int off = (((m >> 4) * 24 + (k >> 5)) * 64 + ((k >> 3) & 3) * 16 + (m & 15)) * 8;
    *(half8*)(xh + off) = hh;
    *(half8*)(xl + off) = ll;
  }
}

// ---- role: xacc(t) = x(t) @ W0x^T  (K=768 x-part of L0, all 4 gates) ----
// 64 blocks x 4 waves; wave = 64 rows (mt) x 16 cols (nt = (b&7)*4 + wv).
DEVINL void run_xgemm(const Params& p, int t, int b /*0..63*/) {
  const _Float16* xh = (t & 1) ? p.xh1 : p.xh0;
  const _Float16* xl = (t & 1) ? p.xl1 : p.xl0;
  float* xacc = (t & 1) ? p.xacc1 : p.xacc0;
  const int lane = threadIdx.x & 63, wv = threadIdx.x >> 6;
  const int lr = lane & 15, lq = lane >> 4;
  const int mt = b >> 3, nt = (b & 7) * 4 + wv;

  f32x4 acc[4][4];
#pragma unroll
  for (int s = 0; s < 4; ++s)
#pragma unroll
    for (int g = 0; g < 4; ++g) acc[s][g] = f32x4{0.f, 0.f, 0.f, 0.f};

  // w0 packed: ((g*32 + nt)*40 + c)*512 + lane*8  (40 chunks: 24 x + 16 rec)
  const _Float16* wpk = p.w0 + (nt * 40) * 512 + lane * 8;
  const _Float16* ah0 = xh + ((mt * 4) * 24) * 512 + lane * 8;  // s stride 24*512
  const _Float16* al0 = xl + ((mt * 4) * 24) * 512 + lane * 8;
  auto addr = [&](int c, int j) -> const _Float16* {
    if (j < 4) return wpk + (j * (32 * 40) + c) * 512;
    if (j < 8) return ah0 + ((j - 4) * 24 + c) * 512;
    return al0 + ((j - 8) * 24 + c) * 512;
  };
  gemm_pipe<24>(acc, addr);

  const int n = nt * 16 + lr;
#pragma unroll
  for (int s = 0; s < 4; ++s) {
    const int mrow = mt * 64 + s * 16 + lq * 4;
#pragma unroll
    for (int g = 0; g < 4; ++g)
#pragma unroll
      for (int r = 0; r < 4; ++r)
        xacc[(mrow + r) * 2048 + g * 512 + n] = acc[s][g][r];
  }
}

// ---- role: recurrent layer step (L0 adds xacc; L1/L2 read prev-layer h) ----
// wave = 64 rows x 16 cols. L0: 64 blocks, L1: 32, L2: 8.
template <int L>
DEVINL void run_rec(const Params& p, int t, int b) {
  constexpr int HH = (L == 0) ? 512 : ((L == 1) ? 256 : 64);
  constexpr int NC = (L == 0) ? 16 : ((L == 1) ? 24 : 10);  // K chunks
  constexpr int NCH = HH / 32;                              // own-h chunks

  const int lane = threadIdx.x & 63, wv = threadIdx.x >> 6;
  const int lr = lane & 15, lq = lane >> 4;
  int mt, nt;
  if constexpr (L == 0)      { mt = b >> 3; nt = (b & 7) * 4 + wv; }
  else if constexpr (L == 1) { mt = b >> 2; nt = (b & 3) * 4 + wv; }
  else                       { mt = b;      nt = wv; }
  const int wbuf = t & 1;

  const _Float16 *hph, *hpl, *pah = nullptr, *pal = nullptr;
  _Float16 *oh, *ol;
  const float *bf1p, *bf2p, *btap, *btbp;
  const _Float16* wpk;
  if constexpr (L == 0) {
    wpk = p.w0 + (nt * 40) * 512 + lane * 8;      // chunks 24..39 = rec part
    hph = wbuf ? p.h0h0 : p.h0h1;  hpl = wbuf ? p.h0l0 : p.h0l1;
    oh  = wbuf ? p.h0h1 : p.h0h0;  ol  = wbuf ? p.h0l1 : p.h0l0;
    bf1p = p.b0f1; bf2p = p.b0f2; btap = p.b0ta; btbp = p.b0tb;
  } else if constexpr (L == 1) {
    wpk = p.w1 + (nt * 24) * 512 + lane * 8;
    pah = wbuf ? p.h0h1 : p.h0h0;  pal = wbuf ? p.h0l1 : p.h0l0;  // h0(t), 16 chunks
    hph = wbuf ? p.h1h0 : p.h1h1;  hpl = wbuf ? p.h1l0 : p.h1l1;  // h1(t-1), 8 chunks
    oh  = wbuf ? p.h1h1 : p.h1h0;  ol  = wbuf ? p.h1l1 : p.h1l0;
    bf1p = p.b1f1; bf2p = p.b1f2; btap = p.b1ta; btbp = p.b1tb;
  } else {
    wpk = p.w2 + (nt * 10) * 512 + lane * 8;
    pah = wbuf ? p.h1h1 : p.h1h0;  pal = wbuf ? p.h1l1 : p.h1l0;  // h1(t), 8 chunks
    hph = wbuf ? p.h2h0 : p.h2h1;  hpl = wbuf ? p.h2l0 : p.h2l1;  // h2(t-1), 2 chunks
    oh  = wbuf ? p.h2h1 : p.h2h0;  ol  = wbuf ? p.h2l1 : p.h2l0;
    bf1p = p.b2f1; bf2p = p.b2f2; btap = p.b2ta; btbp = p.b2tb;
  }

  f32x4 acc[4][4];
#pragma unroll
  for (int s = 0; s < 4; ++s)
#pragma unroll
    for (int g = 0; g < 4; ++g) acc[s][g] = f32x4{0.f, 0.f, 0.f, 0.f};

  const int lane8 = lane * 8;
  const int mt4 = mt * 4;
  auto addr = [&](int c, int j) -> const _Float16* {
    if constexpr (L == 0) {
      if (j < 4) return wpk + (j * (32 * 40) + 24 + c) * 512;
      if (j < 8) return hph + ((mt4 + (j - 4)) * 16 + c) * 512 + lane8;
      return hpl + ((mt4 + (j - 8)) * 16 + c) * 512 + lane8;
    } else if constexpr (L == 1) {
      if (j < 4) return wpk + (j * (16 * 24) + c) * 512;
      const int s = (j < 8) ? (j - 4) : (j - 8);
      const bool hi = (j < 8);
      if (c < 16) return (hi ? pah : pal) + ((mt4 + s) * 16 + c) * 512 + lane8;
      return (hi ? hph : hpl) + ((mt4 + s) * 8 + (c - 16)) * 512 + lane8;
    } else {
      if (j < 4) return wpk + (j * (4 * 10) + c) * 512;
      const int s = (j < 8) ? (j - 4) : (j - 8);
      const bool hi = (j < 8);
      if (c < 8) return (hi ? pah : pal) + ((mt4 + s) * 8 + c) * 512 + lane8;
      return (hi ? hph : hpl) + ((mt4 + s) * 2 + (c - 8)) * 512 + lane8;
    }
  };
  gemm_pipe<NC>(acc, addr);

  const float* xacc = nullptr;
  if constexpr (L == 0) xacc = (t & 1) ? p.xacc1 : p.xacc0;

  const int n = nt * 16 + lr;
  const float bff1 = bf1p[n], bff2 = bf2p[n], bta = btap[n], btb = btbp[n];
#pragma unroll
  for (int s = 0; s < 4; ++s) {
    const int mt16s = mt4 + s;
    // packed h write: off = (mt16s*NCH + n>>5)*512 + ((n>>3)&3)*128 + lrr*8 + (n&7)
    const int obase = (mt16s * NCH + (n >> 5)) * 512 + ((n >> 3) & 3) * 128 + (n & 7);
#pragma unroll
    for (int r = 0; r < 4; ++r) {
      const int row = mt * 64 + s * 16 + lq * 4 + r;
      const int lrr = lq * 4 + r;
      float a0 = acc[s][0][r], a1 = acc[s][1][r], a2 = acc[s][2][r], a3 = acc[s][3][r];
      if constexpr (L == 0) {
        const float* xb = xacc + row * 2048 + n;
        a0 += xb[0]; a1 += xb[512]; a2 += xb[1024]; a3 += xb[1536];
      }
      float vf1 = a0 + bff1;
      float vf2 = a1 + bff2;
      float vt  = (a2 + bta) + (a3 + btb);     // ts = 1.0
      float ff1 = tanhf(vf1);
      float ff2 = tanhf(vf2);
      float ti  = 1.0f / (1.0f + __expf(-vt));
      float hv  = ff1 + ti * (ff2 - ff1);
      _Float16 hh = (_Float16)hv;
      oh[obase + lrr * 8] = hh;
      ol[obase + lrr * 8] = (_Float16)(hv - (float)hh);
      if constexpr (L == 2) {
        if (t == 63) p.out[row * 64 + n] = hv;
      }
    }
  }
}

// roles: [0,48) XPREP(s+2) | [48,112) XGEMM(s+1) | [112,176) L0rec(s)
//        | [176,208) L1(s-1) | [208,216) L2(s-2)
__global__ __launch_bounds__(256, 2) void cfc_step(Params p, int s) {
  const int bid = blockIdx.x;
  if (bid < 48)       { int t = s + 2; if (t >= 0 && t < 64) run_xprep(p, t, bid); }
  else if (bid < 112) { int t = s + 1; if (t >= 0 && t < 64) run_xgemm(p, t, bid - 48); }
  else if (bid < 176) { int t = s;     if (t >= 0 && t < 64) run_rec<0>(p, t, bid - 112); }
  else if (bid < 208) { int t = s - 1; if (t >= 0 && t < 64) run_rec<1>(p, t, bid - 176); }
  else                { int t = s - 2; if (t >= 0 && t < 64) run_rec<2>(p, t, bid - 208); }
}

// pack weights: dst[((nt*NCk + c)*64 + lane)*8 + e] = w[n][k]*mask[n][k]
// with n = nt*16 + (lane&15), k = c*32 + (lane>>4)*8 + e, NCk = WK/32.
__global__ void prep_w_pk(const float* __restrict__ w, const float* __restrict__ mask,
                          _Float16* __restrict__ dst, int WK, int total) {
  int i = blockIdx.x * 256 + threadIdx.x;
  if (i >= total) return;
  int e = i & 7, lane = (i >> 3) & 63, rem = i >> 9;
  int NCk = WK >> 5;
  int c = rem % NCk, nt = rem / NCk;
  int n = nt * 16 + (lane & 15);
  int k = c * 32 + (lane >> 4) * 8 + e;
  float v = w[n * WK + k];
  if (mask) v *= mask[n * WK + k];
  dst[i] = (_Float16)v;
}

__global__ void zero_kernel(unsigned* __restrict__ p, int n) {
  int i = blockIdx.x * 256 + threadIdx.x;
  if (i < n) p[i] = 0u;
}

extern "C" void kernel_launch(void* const* d_in, const int* in_sizes, int n_in,
                              void* d_out, int out_size, void* d_ws, size_t ws_size,
                              hipStream_t stream) {
  // ---- workspace layout (units: _Float16); packed sizes == old sizes ----
  _Float16* w0  = (_Float16*)d_ws;          // 4*512*1280 = 2,621,440
  _Float16* w1  = w0 + 2621440;             // 4*256*768  =   786,432
  _Float16* w2  = w1 + 786432;              // 4*64*320   =    81,920
  _Float16* xh0 = w2 + 81920;               // 512*768 per buffer
  _Float16* xl0 = xh0 + 393216;
  _Float16* xh1 = xl0 + 393216;
  _Float16* xl1 = xh1 + 393216;
  _Float16* hb  = xl1 + 393216;             // h region (zeroed)
  _Float16* h0h0 = hb;            _Float16* h0h1 = h0h0 + 262144;
  _Float16* h0l0 = h0h1 + 262144; _Float16* h0l1 = h0l0 + 262144;
  _Float16* h1h0 = h0l1 + 262144; _Float16* h1h1 = h1h0 + 131072;
  _Float16* h1l0 = h1h1 + 131072; _Float16* h1l1 = h1l0 + 131072;
  _Float16* h2h0 = h1l1 + 131072; _Float16* h2h1 = h2h0 + 32768;
  _Float16* h2l0 = h2h1 + 32768;  _Float16* h2l1 = h2l0 + 32768;
  float* xacc0 = (float*)(h2l1 + 32768);    // 512*2048 fp32 per buffer
  float* xacc1 = xacc0 + 1048576;           // total ws ≈ 21.9 MB

  // zero h ping-pong planes (ws is poisoned 0xAA before every call)
  const int h_uints = 1703936 / 2;
  zero_kernel<<<(h_uints + 255) / 256, 256, 0, stream>>>((unsigned*)hb, h_uints);

  const float* F = nullptr;
  auto in = [&](int i) { return (const float*)d_in[i]; };

  // weights -> fp16 packed (masked on ff1/ff2); gate order [ff1,ff2,ta,tb]
  prep_w_pk<<<2560, 256, 0, stream>>>(in(2),  in(10), w0 + 0 * 655360, 1280, 655360);
  prep_w_pk<<<2560, 256, 0, stream>>>(in(4),  in(10), w0 + 1 * 655360, 1280, 655360);
  prep_w_pk<<<2560, 256, 0, stream>>>(in(6),  F,      w0 + 2 * 655360, 1280, 655360);
  prep_w_pk<<<2560, 256, 0, stream>>>(in(8),  F,      w0 + 3 * 655360, 1280, 655360);
  prep_w_pk<<<768,  256, 0, stream>>>(in(11), in(19), w1 + 0 * 196608, 768,  196608);
  prep_w_pk<<<768,  256, 0, stream>>>(in(13), in(19), w1 + 1 * 196608, 768,  196608);
  prep_w_pk<<<768,  256, 0, stream>>>(in(15), F,      w1 + 2 * 196608, 768,  196608);
  prep_w_pk<<<768,  256, 0, stream>>>(in(17), F,      w1 + 3 * 196608, 768,  196608);
  prep_w_pk<<<80,   256, 0, stream>>>(in(20), in(28), w2 + 0 * 20480,  320,  20480);
  prep_w_pk<<<80,   256, 0, stream>>>(in(22), in(28), w2 + 1 * 20480,  320,  20480);
  prep_w_pk<<<80,   256, 0, stream>>>(in(24), F,      w2 + 2 * 20480,  320,  20480);
  prep_w_pk<<<80,   256, 0, stream>>>(in(26), F,      w2 + 3 * 20480,  320,  20480);

  Params p;
  p.base = in(0); p.visual = in(1);
  p.w0 = w0; p.w1 = w1; p.w2 = w2;
  p.b0f1 = in(3);  p.b0f2 = in(5);  p.b0ta = in(7);  p.b0tb = in(9);
  p.b1f1 = in(12); p.b1f2 = in(14); p.b1ta = in(16); p.b1tb = in(18);
  p.b2f1 = in(21); p.b2f2 = in(23); p.b2ta = in(25); p.b2tb = in(27);
  p.xh0 = xh0; p.xl0 = xl0; p.xh1 = xh1; p.xl1 = xl1;
  p.xacc0 = xacc0; p.xacc1 = xacc1;
  p.h0h0 = h0h0; p.h0h1 = h0h1; p.h0l0 = h0l0; p.h0l1 = h0l1;
  p.h1h0 = h1h0; p.h1h1 = h1h1; p.h1l0 = h1l0; p.h1l1 = h1l1;
  p.h2h0 = h2h0; p.h2h1 = h2h1; p.h2l0 = h2l0; p.h2l1 = h2l1;
  p.out = (float*)d_out;

  // pipeline: s=-2..65; XPREP t=s+2, XGEMM t=s+1, L0 t=s, L1 t=s-1, L2 t=s-2
  for (int s = -2; s < 66; ++s) {
    cfc_step<<<216, 256, 0, stream>>>(p, s);
  }
}

// Round 9
// 1162.409 us; speedup vs baseline: 1.1712x; 1.1712x over previous
//
#include <hip/hip_runtime.h>
#include <cmath>

// CfC encoder: 3-layer liquid-NN recurrence, B=512, K=64 steps, fp32 io.
// R11: traffic attack. R6-R10 established the per-dispatch floor tracks
// L2-boundary traffic (~30 MB @ ~1.6 TB/s fill), not latency/ILP/occupancy/
// instruction count. This version FUSES the x-part GEMM into L0 (full
// K=1280 = 24 x-chunks + 16 rec-chunks per wave), deleting the 8 MB/step
// xacc fp32 round trip (27% of traffic) and one pipeline stage.
// Roles per step s: XPREP(s+1) | L0full(s) | L1(s-1) | L2(s-2).

typedef __attribute__((ext_vector_type(8))) _Float16 half8;
typedef __attribute__((ext_vector_type(4))) float f32x4;

#define DEVINL __device__ __forceinline__

struct Params {
  const float* base;    // (512,64,256)
  const float* visual;  // (512,64,512)
  const _Float16 *w0, *w1, *w2;   // packed [g][nt][c][lane][8]
  const float *b0f1,*b0f2,*b0ta,*b0tb;
  const float *b1f1,*b1f2,*b1ta,*b1tb;
  const float *b2f1,*b2f2,*b2ta,*b2tb;
  _Float16 *xh0,*xl0,*xh1,*xl1;   // x planes packed [mt16][c(24)][lane][8]
  _Float16 *h0h0,*h0h1,*h0l0,*h0l1;   // h planes packed [mt16][c(HH/32)][lane][8]
  _Float16 *h1h0,*h1h1,*h1l0,*h1l1;
  _Float16 *h2h0,*h2h1,*h2l0,*h2l1;
  float* out;
};

// ---- asm load + counted-vmcnt wait primitives ----
DEVINL void gload(half8& d, const _Float16* a) {
  asm volatile("global_load_dwordx4 %0, %1, off" : "=v"(d) : "v"(a));
}
template <int V>
DEVINL void vmwait() {
  // gfx9 waitcnt encoding: vmcnt[3:0]|expcnt[6:4]|lgkmcnt[11:8]|vmcnt_hi[15:14]
  __builtin_amdgcn_s_waitcnt((V & 15) | (7 << 4) | (15 << 8) | ((V >> 4) << 14));
  __builtin_amdgcn_sched_barrier(0);   // rule #18: stop MFMA hoist above wait
}

// ---- depth-4 ring pipelined GEMM over NC k-chunks ----
// addr(c, j): j=0..3 weight gate frag, j=4 act-hi frag, j=5 act-lo frag.
template <int C, int NC, int D, class AF>
DEVINL void pipe_iter(half8 (&buf)[D][6], f32x4 (&acc)[4], const AF& addr) {
  constexpr int issued = (C + D < NC) ? (C + D) : NC;
  vmwait<6 * (issued - C - 1)>();      // oldest chunk (C) has landed
  {
    half8 b0 = buf[C % D][0], b1 = buf[C % D][1];
    half8 b2 = buf[C % D][2], b3 = buf[C % D][3];
    half8 ah = buf[C % D][4], al = buf[C % D][5];
    acc[0] = __builtin_amdgcn_mfma_f32_16x16x32_f16(ah, b0, acc[0], 0, 0, 0);
    acc[0] = __builtin_amdgcn_mfma_f32_16x16x32_f16(al, b0, acc[0], 0, 0, 0);
    acc[1] = __builtin_amdgcn_mfma_f32_16x16x32_f16(ah, b1, acc[1], 0, 0, 0);
    acc[1] = __builtin_amdgcn_mfma_f32_16x16x32_f16(al, b1, acc[1], 0, 0, 0);
    acc[2] = __builtin_amdgcn_mfma_f32_16x16x32_f16(ah, b2, acc[2], 0, 0, 0);
    acc[2] = __builtin_amdgcn_mfma_f32_16x16x32_f16(al, b2, acc[2], 0, 0, 0);
    acc[3] = __builtin_amdgcn_mfma_f32_16x16x32_f16(ah, b3, acc[3], 0, 0, 0);
    acc[3] = __builtin_amdgcn_mfma_f32_16x16x32_f16(al, b3, acc[3], 0, 0, 0);
  }
  if constexpr (C + D < NC) {
#pragma unroll
    for (int j = 0; j < 6; ++j) gload(buf[C % D][j], addr(C + D, j));
  }
  if constexpr (C + 1 < NC) pipe_iter<C + 1, NC, D>(buf, acc, addr);
}

template <int NC, class AF>
DEVINL void gemm_pipe(f32x4 (&acc)[4], const AF& addr) {
  constexpr int D = (NC < 4) ? NC : 4;
  half8 buf[D][6];
#pragma unroll
  for (int c = 0; c < D; ++c)
#pragma unroll
    for (int j = 0; j < 6; ++j) gload(buf[c][j], addr(c, j));
  pipe_iter<0, NC, D>(buf, acc, addr);
}

// ---- role: split x(t) fp32 -> fp16 hi/lo packed planes (buf t&1) ----
DEVINL void run_xprep(const Params& p, int t, int b /*0..47*/) {
  _Float16* xh = (t & 1) ? p.xh1 : p.xh0;
  _Float16* xl = (t & 1) ? p.xl1 : p.xl0;
  int tid = b * 256 + threadIdx.x;            // 12288 threads
#pragma unroll
  for (int i = tid; i < 49152; i += 12288) {  // 512 rows * 96 groups of 8
    int m = i / 96;
    int k = (i - m * 96) * 8;
    const float* src = (k < 256) ? (p.base + (m * 64 + t) * 256 + k)
                                 : (p.visual + (m * 64 + t) * 512 + (k - 256));
    const f32x4* q = (const f32x4*)src;
    f32x4 v0 = q[0], v1 = q[1];
    half8 hh, ll;
#pragma unroll
    for (int j = 0; j < 4; ++j) {
      _Float16 a = (_Float16)v0[j]; hh[j] = a;     ll[j]     = (_Float16)(v0[j] - (float)a);
      _Float16 c = (_Float16)v1[j]; hh[j + 4] = c; ll[j + 4] = (_Float16)(v1[j] - (float)c);
    }
    // packed: [mt16 = m>>4][c = k>>5][lane = ((k>>3)&3)*16 + (m&15)][8]
    int off = (((m >> 4) * 24 + (k >> 5)) * 64 + ((k >> 3) & 3) * 16 + (m & 15)) * 8;
    *(half8*)(xh + off) = hh;
    *(half8*)(xl + off) = ll;
  }
}

// ---- role: recurrent layer step ----
// L0: FULL K=1280 (chunks 0..23 = x planes, 24..39 = h0 rec) -> no xacc.
// L1/L2: prev-layer h + own rec, as before. 64-row M tiles:
// L0 256 blocks, L1 128, L2 32.
template <int L>
DEVINL void run_rec(const Params& p, int t, int b) {
  constexpr int HH = (L == 0) ? 512 : ((L == 1) ? 256 : 64);
  constexpr int NC = (L == 0) ? 40 : ((L == 1) ? 24 : 10);  // K chunks
  constexpr int NCH = HH / 32;                              // own-h chunks

  const int lane = threadIdx.x & 63, wv = threadIdx.x >> 6;
  const int lr = lane & 15, lq = lane >> 4;
  int mt, nt;
  if constexpr (L == 0)      { mt = b >> 5; nt = b & 31; }
  else if constexpr (L == 1) { mt = b >> 4; nt = b & 15; }
  else                       { mt = b >> 2; nt = b & 3; }
  const int m_base = mt * 64 + wv * 16, n0 = nt * 16;
  const int mt16 = mt * 4 + wv;
  const int wbuf = t & 1;

  const _Float16 *hph, *hpl, *pah = nullptr, *pal = nullptr;
  _Float16 *oh, *ol;
  const float *bf1p, *bf2p, *btap, *btbp;
  const _Float16* wpk;
  if constexpr (L == 0) {
    wpk = p.w0 + (nt * 40) * 512 + lane * 8;      // all 40 chunks (x + rec)
    pah = wbuf ? p.xh1 : p.xh0;    pal = wbuf ? p.xl1 : p.xl0;    // x(t), 24 chunks
    hph = wbuf ? p.h0h0 : p.h0h1;  hpl = wbuf ? p.h0l0 : p.h0l1;  // h0(t-1), 16 chunks
    oh  = wbuf ? p.h0h1 : p.h0h0;  ol  = wbuf ? p.h0l1 : p.h0l0;
    bf1p = p.b0f1; bf2p = p.b0f2; btap = p.b0ta; btbp = p.b0tb;
  } else if constexpr (L == 1) {
    wpk = p.w1 + (nt * 24) * 512 + lane * 8;
    pah = wbuf ? p.h0h1 : p.h0h0;  pal = wbuf ? p.h0l1 : p.h0l0;  // h0(t), 16 chunks
    hph = wbuf ? p.h1h0 : p.h1h1;  hpl = wbuf ? p.h1l0 : p.h1l1;  // h1(t-1), 8 chunks
    oh  = wbuf ? p.h1h1 : p.h1h0;  ol  = wbuf ? p.h1l1 : p.h1l0;
    bf1p = p.b1f1; bf2p = p.b1f2; btap = p.b1ta; btbp = p.b1tb;
  } else {
    wpk = p.w2 + (nt * 10) * 512 + lane * 8;
    pah = wbuf ? p.h1h1 : p.h1h0;  pal = wbuf ? p.h1l1 : p.h1l0;  // h1(t), 8 chunks
    hph = wbuf ? p.h2h0 : p.h2h1;  hpl = wbuf ? p.h2l0 : p.h2l1;  // h2(t-1), 2 chunks
    oh  = wbuf ? p.h2h1 : p.h2h0;  ol  = wbuf ? p.h2l1 : p.h2l0;
    bf1p = p.b2f1; bf2p = p.b2f2; btap = p.b2ta; btbp = p.b2tb;
  }

  f32x4 acc[4];
#pragma unroll
  for (int g = 0; g < 4; ++g) acc[g] = f32x4{0.f, 0.f, 0.f, 0.f};

  const int lane8 = lane * 8;
  auto addr = [&](int c, int j) -> const _Float16* {
    if constexpr (L == 0) {
      if (j < 4) return wpk + (j * (32 * 40) + c) * 512;
      if (c < 24) return ((j == 4) ? pah : pal) + (mt16 * 24 + c) * 512 + lane8;
      return ((j == 4) ? hph : hpl) + (mt16 * 16 + (c - 24)) * 512 + lane8;
    } else if constexpr (L == 1) {
      if (j < 4) return wpk + (j * (16 * 24) + c) * 512;
      if (c < 16) return ((j == 4) ? pah : pal) + (mt16 * 16 + c) * 512 + lane8;
      return ((j == 4) ? hph : hpl) + (mt16 * 8 + (c - 16)) * 512 + lane8;
    } else {
      if (j < 4) return wpk + (j * (4 * 10) + c) * 512;
      if (c < 8) return ((j == 4) ? pah : pal) + (mt16 * 8 + c) * 512 + lane8;
      return ((j == 4) ? hph : hpl) + (mt16 * 2 + (c - 8)) * 512 + lane8;
    }
  };
  gemm_pipe<NC>(acc, addr);

  const int n = n0 + lr;
  const float bff1 = bf1p[n], bff2 = bf2p[n], bta = btap[n], btb = btbp[n];
  // packed h write: off = (mt16*NCH + n>>5)*512 + ((n>>3)&3)*128 + lrr*8 + (n&7)
  const int obase = ((m_base >> 4) * NCH + (n >> 5)) * 512 + ((n >> 3) & 3) * 128 + (n & 7);
#pragma unroll
  for (int r = 0; r < 4; ++r) {
    const int row = m_base + lq * 4 + r;
    const int lrr = lq * 4 + r;
    float a0 = acc[0][r], a1 = acc[1][r], a2 = acc[2][r], a3 = acc[3][r];
    float vf1 = a0 + bff1;
    float vf2 = a1 + bff2;
    float vt  = (a2 + bta) + (a3 + btb);     // ts = 1.0
    float ff1 = tanhf(vf1);
    float ff2 = tanhf(vf2);
    float ti  = 1.0f / (1.0f + __expf(-vt));
    float hv  = ff1 + ti * (ff2 - ff1);
    _Float16 hh = (_Float16)hv;
    oh[obase + lrr * 8] = hh;
    ol[obase + lrr * 8] = (_Float16)(hv - (float)hh);
    if constexpr (L == 2) {
      if (t == 63) p.out[row * 64 + n] = hv;
    }
  }
}

// roles: [0,48) XPREP(s+1) | [48,304) L0full(s) | [304,432) L1(s-1)
//        | [432,464) L2(s-2)
__global__ __launch_bounds__(256, 2) void cfc_step(Params p, int s) {
  const int bid = blockIdx.x;
  if (bid < 48)       { int t = s + 1; if (t >= 0 && t < 64) run_xprep(p, t, bid); }
  else if (bid < 304) { int t = s;     if (t >= 0 && t < 64) run_rec<0>(p, t, bid - 48); }
  else if (bid < 432) { int t = s - 1; if (t >= 0 && t < 64) run_rec<1>(p, t, bid - 304); }
  else                { int t = s - 2; if (t >= 0 && t < 64) run_rec<2>(p, t, bid - 432); }
}

// pack weights: dst[((nt*NCk + c)*64 + lane)*8 + e] = w[n][k]*mask[n][k]
// with n = nt*16 + (lane&15), k = c*32 + (lane>>4)*8 + e, NCk = WK/32.
__global__ void prep_w_pk(const float* __restrict__ w, const float* __restrict__ mask,
                          _Float16* __restrict__ dst, int WK, int total) {
  int i = blockIdx.x * 256 + threadIdx.x;
  if (i >= total) return;
  int e = i & 7, lane = (i >> 3) & 63, rem = i >> 9;
  int NCk = WK >> 5;
  int c = rem % NCk, nt = rem / NCk;
  int n = nt * 16 + (lane & 15);
  int k = c * 32 + (lane >> 4) * 8 + e;
  float v = w[n * WK + k];
  if (mask) v *= mask[n * WK + k];
  dst[i] = (_Float16)v;
}

__global__ void zero_kernel(unsigned* __restrict__ p, int n) {
  int i = blockIdx.x * 256 + threadIdx.x;
  if (i < n) p[i] = 0u;
}

extern "C" void kernel_launch(void* const* d_in, const int* in_sizes, int n_in,
                              void* d_out, int out_size, void* d_ws, size_t ws_size,
                              hipStream_t stream) {
  // ---- workspace layout (units: _Float16); xacc removed ----
  _Float16* w0  = (_Float16*)d_ws;          // 4*512*1280 = 2,621,440
  _Float16* w1  = w0 + 2621440;             // 4*256*768  =   786,432
  _Float16* w2  = w1 + 786432;              // 4*64*320   =    81,920
  _Float16* xh0 = w2 + 81920;               // 512*768 per buffer
  _Float16* xl0 = xh0 + 393216;
  _Float16* xh1 = xl0 + 393216;
  _Float16* xl1 = xh1 + 393216;
  _Float16* hb  = xl1 + 393216;             // h region (zeroed)
  _Float16* h0h0 = hb;            _Float16* h0h1 = h0h0 + 262144;
  _Float16* h0l0 = h0h1 + 262144; _Float16* h0l1 = h0l0 + 262144;
  _Float16* h1h0 = h0l1 + 262144; _Float16* h1h1 = h1h0 + 131072;
  _Float16* h1l0 = h1h1 + 131072; _Float16* h1l1 = h1l0 + 131072;
  _Float16* h2h0 = h1l1 + 131072; _Float16* h2h1 = h2h0 + 32768;
  _Float16* h2l0 = h2h1 + 32768;  _Float16* h2l1 = h2l0 + 32768;
  // total ws ~= 13.9 MB

  // zero h ping-pong planes (ws is poisoned 0xAA before every call)
  const int h_uints = 1703936 / 2;
  zero_kernel<<<(h_uints + 255) / 256, 256, 0, stream>>>((unsigned*)hb, h_uints);

  const float* F = nullptr;
  auto in = [&](int i) { return (const float*)d_in[i]; };

  // weights -> fp16 packed (masked on ff1/ff2); gate order [ff1,ff2,ta,tb]
  prep_w_pk<<<2560, 256, 0, stream>>>(in(2),  in(10), w0 + 0 * 655360, 1280, 655360);
  prep_w_pk<<<2560, 256, 0, stream>>>(in(4),  in(10), w0 + 1 * 655360, 1280, 655360);
  prep_w_pk<<<2560, 256, 0, stream>>>(in(6),  F,      w0 + 2 * 655360, 1280, 655360);
  prep_w_pk<<<2560, 256, 0, stream>>>(in(8),  F,      w0 + 3 * 655360, 1280, 655360);
  prep_w_pk<<<768,  256, 0, stream>>>(in(11), in(19), w1 + 0 * 196608, 768,  196608);
  prep_w_pk<<<768,  256, 0, stream>>>(in(13), in(19), w1 + 1 * 196608, 768,  196608);
  prep_w_pk<<<768,  256, 0, stream>>>(in(15), F,      w1 + 2 * 196608, 768,  196608);
  prep_w_pk<<<768,  256, 0, stream>>>(in(17), F,      w1 + 3 * 196608, 768,  196608);
  prep_w_pk<<<80,   256, 0, stream>>>(in(20), in(28), w2 + 0 * 20480,  320,  20480);
  prep_w_pk<<<80,   256, 0, stream>>>(in(22), in(28), w2 + 1 * 20480,  320,  20480);
  prep_w_pk<<<80,   256, 0, stream>>>(in(24), F,      w2 + 2 * 20480,  320,  20480);
  prep_w_pk<<<80,   256, 0, stream>>>(in(26), F,      w2 + 3 * 20480,  320,  20480);

  Params p;
  p.base = in(0); p.visual = in(1);
  p.w0 = w0; p.w1 = w1; p.w2 = w2;
  p.b0f1 = in(3);  p.b0f2 = in(5);  p.b0ta = in(7);  p.b0tb = in(9);
  p.b1f1 = in(12); p.b1f2 = in(14); p.b1ta = in(16); p.b1tb = in(18);
  p.b2f1 = in(21); p.b2f2 = in(23); p.b2ta = in(25); p.b2tb = in(27);
  p.xh0 = xh0; p.xl0 = xl0; p.xh1 = xh1; p.xl1 = xl1;
  p.h0h0 = h0h0; p.h0h1 = h0h1; p.h0l0 = h0l0; p.h0l1 = h0l1;
  p.h1h0 = h1h0; p.h1h1 = h1h1; p.h1l0 = h1l0; p.h1l1 = h1l1;
  p.h2h0 = h2h0; p.h2h1 = h2h1; p.h2l0 = h2l0; p.h2l1 = h2l1;
  p.out = (float*)d_out;

  // pipeline: s=-1..65; XPREP t=s+1, L0full t=s, L1 t=s-1, L2 t=s-2
  for (int s = -1; s < 66; ++s) {
    cfc_step<<<464, 256, 0, stream>>>(p, s);
  }
}